// Round 8
// baseline (145.816 us; speedup 1.0000x reference)
//
#include <hip/hip_runtime.h>
#include <hip/hip_fp16.h>

// Batched quantum-circuit sim. ONE launch, 256-thread blocks (R6's exact
// proven launch attributes), each block owns a 64-element chunk with
// per-wave roles:
//   wave 0: sims A+B (1 lane/elem)   -> out[b*9 + 0..3]
//   wave 3: sim C    (1 lane/elem)   -> out[b*9 + 4..5]
//   waves 1,2: 7q (2 lanes/elem, qubit0 = lane parity) -> out[b*9 + 6..8]
// All writers of an output line are in ONE block (R6 measured 18MB WRITE vs
// 4.7MB ideal from 4 cross-block writers per line); x-rows L1-shared.
// State in ext_vector_type SSA vectors (R6: state register-resident, VGPR 76).

#define DEVINL __device__ __forceinline__

typedef _Float16 hv2 __attribute__((ext_vector_type(2)));
typedef unsigned int u32;
typedef u32 vreg16 __attribute__((ext_vector_type(16)));
typedef u32 vreg64 __attribute__((ext_vector_type(64)));

struct C2 { __half2 rr, mp; };  // complex const (r,i): rr=(r,r), mp=(-i,+i)

DEVINL C2 mkc(float re, float im) {
  C2 c; c.rr = __floats2half2_rn(re, re); c.mp = __floats2half2_rn(-im, im); return c;
}
DEVINL __half2 mkamp(float re, float im) { return __floats2half2_rn(re, im); }
DEVINL __half2 swap2(__half2 v) { return __lowhigh2highlow(v); }
// (const u) * (amp v):  (r*vr - i*vi, r*vi + i*vr)
DEVINL __half2 cmulc(C2 u, __half2 v) { return __hfma2(u.rr, v, __hmul2(u.mp, swap2(v))); }

DEVINL float ampsq(__half2 v, float acc) {
#if __has_builtin(__builtin_amdgcn_fdot2)
  return __builtin_amdgcn_fdot2(__builtin_bit_cast(hv2, v), __builtin_bit_cast(hv2, v), acc, false);
#else
  float2 f = __half22float2(v);
  return fmaf(f.x, f.x, fmaf(f.y, f.y, acc));
#endif
}

constexpr int parc(int x) { x ^= x >> 4; x ^= x >> 2; x ^= x >> 1; return x & 1; }

struct c32 { float x, y; };
DEVINL c32 cmulf(c32 a, c32 b) { return { a.x*b.x - a.y*b.y, a.x*b.y + a.y*b.x }; }

// ---- SSA state accessors (constant-index extract/insert) -------------------
template<class VT>
DEVINL __half2 vget(const VT& A, int i) { return __builtin_bit_cast(__half2, (u32)A[i]); }
template<class VT>
DEVINL void vset(VT& A, int i, __half2 v) { A[i] = __builtin_bit_cast(u32, v); }

// ---- lane^1 exchange via shfl_xor (verified path from R3) ------------------
DEVINL __half2 lx1(__half2 v) {
  int q = __shfl_xor(__builtin_bit_cast(int, v), 1, 64);
  return __builtin_bit_cast(__half2, q);
}
DEVINL float lx1f(float v) { return __shfl_xor(v, 1, 64); }

// ---------------- generic gates (qubit W of N; mask = 1<<(N-1-W)) -----------

template<int N, int W, class VT>
DEVINL void g_ry(VT& A, __half2 c2, __half2 s2, __half2 ns2) {
  constexpr int M = 1 << (N - 1 - W);
#pragma unroll
  for (int i = 0; i < (1 << N); ++i) if (!(i & M)) {
    const int j = i | M;
    __half2 v0 = vget(A, i), v1 = vget(A, j);
    vset(A, i, __hfma2(c2, v0, __hmul2(ns2, v1)));
    vset(A, j, __hfma2(c2, v1, __hmul2(s2, v0)));
  }
}

template<int N, int W, class VT>
DEVINL void g_u2(VT& A, C2 u00, C2 u01, C2 u10, C2 u11) {
  constexpr int M = 1 << (N - 1 - W);
#pragma unroll
  for (int i = 0; i < (1 << N); ++i) if (!(i & M)) {
    const int j = i | M;
    __half2 v0 = vget(A, i), v1 = vget(A, j), v0s = swap2(v0), v1s = swap2(v1);
    vset(A, i, __hfma2(u00.rr, v0, __hfma2(u00.mp, v0s, __hfma2(u01.rr, v1, __hmul2(u01.mp, v1s)))));
    vset(A, j, __hfma2(u10.rr, v0, __hfma2(u10.mp, v0s, __hfma2(u11.rr, v1, __hmul2(u11.mp, v1s)))));
  }
}

template<int N, int C, int T, class VT>
DEVINL void g_cnot(VT& A) {
  constexpr int CM = 1 << (N - 1 - C), TM = 1 << (N - 1 - T);
#pragma unroll
  for (int i = 0; i < (1 << N); ++i) if ((i & CM) && !(i & TM)) {
    const int j = i | TM;
    __half2 t = vget(A, i); vset(A, i, vget(A, j)); vset(A, j, t);
  }
}

template<int N, int K, class VT>
DEVINL void chain_cnot(VT& A) {
  if constexpr (K < N - 1) { g_cnot<N, K, K + 1>(A); chain_cnot<N, K + 1>(A); }
}

// ---------------- per-qubit coefficients (f32) ------------------------------
// forward: u = Rz(phi)Ry(pt)Rx(eta)|0>;  reverse merged: U = Rx(phi)Ry(pt)Rz(eta)

DEVINL void mk_u01(float ce, float se, float cp, float sp, float cf, float sf,
                   c32& u0, c32& u1) {
  u0 = cmulf({cf, -sf}, {cp * ce, sp * se});
  u1 = cmulf({cf,  sf}, {sp * ce, -cp * se});
}

DEVINL void mk_U(float ce, float se, float cp, float sp, float cf, float sf,
                 C2& U00, C2& U01, C2& U10, C2& U11) {
  c32 z = {ce, -se}, zb = {ce, se};
  c32 A = cmulf({cf * cp, -sf * sp}, z);
  c32 T = cmulf({cf * sp,  sf * cp}, zb);
  c32 Cc = cmulf({cf * sp, -sf * cp}, z);
  c32 D = cmulf({cf * cp,  sf * sp}, zb);
  U00 = mkc(A.x, A.y); U01 = mkc(-T.x, -T.y); U10 = mkc(Cc.x, Cc.y); U11 = mkc(D.x, D.y);
}

// per-qubit sincos loader (eta_i<0 -> eta=0)
DEVINL void load_sc(const float* __restrict__ xr, int eta_i, int pt_i, int phi_i,
                    float& ce, float& se, float& cp, float& sp, float& cf, float& sf) {
  float e = (eta_i < 0) ? 0.f : xr[eta_i];
  __sincosf(0.5f * e, &se, &ce);
  __sincosf(0.5f * xr[pt_i], &sp, &cp);
  __sincosf(0.5f * xr[phi_i], &sf, &cf);
}

// product state build by doubling (A[0] must be (1,0) on entry).
// step M's qubit lands at bit (N-1-M). CF(M,u0,u1) supplies the column.
template<int N, int M, class VT, class CF>
DEVINL void build_rec(VT& A, CF cf) {
  if constexpr (M < N) {
    c32 u0, u1; cf(M, u0, u1);
    C2 c0 = mkc(u0.x, u0.y), c1 = mkc(u1.x, u1.y);
#pragma unroll
    for (int j = (1 << M) - 1; j >= 0; --j) {
      __half2 s = vget(A, j);
      vset(A, 2 * j,     cmulc(c0, s));
      vset(A, 2 * j + 1, cmulc(c1, s));
    }
    build_rec<N, M + 1>(A, cf);
  }
}

template<int N, int K, class VT, class CF>
DEVINL void usweep_rec(VT& A, CF cf) {
  if constexpr (K < N) {
    C2 U00, U01, U10, U11;
    cf(K, U00, U01, U10, U11);
    g_u2<N, K>(A, U00, U01, U10, U11);
    usweep_rec<N, K + 1>(A, cf);
  }
}

template<int N, int K, class VT, class CF>
DEVINL void ry_rec(VT& A, CF cf) {
  if constexpr (K < N) {
    __half2 c2, s2, ns2;
    cf(K, c2, s2, ns2);
    g_ry<N, K>(A, c2, s2, ns2);
    ry_rec<N, K + 1>(A, cf);
  }
}

// ---------------- 4-qubit block I (verified math, SSA state) ----------------

template<int I>
DEVINL void sim4h(const float* __restrict__ xr, const float* __restrict__ w, float* z) {
  constexpr int PT[3][4]  = {{5, 4, 35, 34}, {3, 33, 31, 2}, {28, 32, 15, 16}};
  constexpr int ETA[3][4] = {{9, 8, 45, 44}, {7, 43, 41, 6}, {38, 42, 19, 20}};
  constexpr int PHI[3][4] = {{13, 12, 55, 54}, {11, 53, 51, 10}, {48, 52, 23, 24}};
  vreg16 A;
  vset(A, 0, mkamp(1.f, 0.f));
  build_rec<4, 0>(A, [&](int M, c32& u0, c32& u1) {
    float ce, se, cp, sp, cf, sf;
    load_sc(xr, ETA[I][M], PT[I][M], PHI[I][M], ce, se, cp, sp, cf, sf);
    mk_u01(ce, se, cp, sp, cf, sf, u0, u1);
  });
  chain_cnot<4, 0>(A);
  usweep_rec<4, 0>(A, [&](int K, C2& U00, C2& U01, C2& U10, C2& U11) {
    float ce, se, cp, sp, cf, sf;
    load_sc(xr, ETA[I][K], PT[I][K], PHI[I][K], ce, se, cp, sp, cf, sf);
    mk_U(ce, se, cp, sp, cf, sf, U00, U01, U10, U11);
  });

  // t->l CNOT block == flip q0,q1 (mask 12) iff parity(b2,b3) (i&3)
#pragma unroll
  for (int i = 0; i < 16; ++i)
    if (parc(i & 3) && !(i & 8)) {
      __half2 t = vget(A, i); vset(A, i, vget(A, i ^ 12)); vset(A, i ^ 12, t);
    }

  ry_rec<4, 0>(A, [&](int K, __half2& c2, __half2& s2, __half2& ns2) {
    float sv, cv; __sincosf(0.5f * w[K], &sv, &cv);
    c2 = __floats2half2_rn(cv, cv);
    s2 = __floats2half2_rn(sv, sv);
    ns2 = __floats2half2_rn(-sv, -sv);
  });

  // l->t CNOT block == flip q2,q3 (mask 3) iff parity(b0,b1) (i&12)
#pragma unroll
  for (int i = 0; i < 16; ++i)
    if (parc(i & 12) && !(i & 2)) {
      __half2 t = vget(A, i); vset(A, i, vget(A, i ^ 3)); vset(A, i ^ 3, t);
    }

  float cls[4];
#pragma unroll
  for (int c = 0; c < 4; ++c) cls[c] = 0.f;
#pragma unroll
  for (int i = 0; i < 16; ++i) cls[i & 3] = ampsq(vget(A, i), cls[i & 3]);
  float z0 = 0.f, z1 = 0.f;
#pragma unroll
  for (int c = 0; c < 4; ++c) {
    z0 += (c & 2) ? -cls[c] : cls[c];
    z1 += (c & 1) ? -cls[c] : cls[c];
  }
  z[0] = z0; z[1] = z1;
}

// ---------------- 7q body (2 lanes/element; verified R3/R6 math) ------------

DEVINL void role7(const float* __restrict__ xr, const float* __restrict__ wD,
                  float* __restrict__ out_row, bool po) {
  constexpr int PT[7]  = {0, 14, 30, 26, 29, 27, 17};
  constexpr int ETA[7] = {-1, 18, 40, 36, 39, 37, 21};  // -1 -> zeros (None)
  constexpr int PHI[7] = {1, 22, 50, 46, 49, 47, 25};

  vreg64 A;
  vset(A, 0, mkamp(1.f, 0.f));
  // build qubits 1..6 locally: step M = qubit M+1 -> local bit 5-M = 6-(M+1)
  build_rec<6, 0>(A, [&](int M, c32& u0, c32& u1) {
    const int k = M + 1;
    float ce, se, cp, sp, cf, sf;
    load_sc(xr, ETA[k], PT[k], PHI[k], ce, se, cp, sp, cf, sf);
    mk_u01(ce, se, cp, sp, cf, sf, u0, u1);
  });
  { // qubit-0 product factor, selected by lane parity
    float ce, se, cp, sp, cf, sf;
    load_sc(xr, ETA[0], PT[0], PHI[0], ce, se, cp, sp, cf, sf);
    c32 u0, u1; mk_u01(ce, se, cp, sp, cf, sf, u0, u1);
    C2 c0 = mkc(po ? u1.x : u0.x, po ? u1.y : u0.y);
#pragma unroll
    for (int i = 0; i < 64; ++i) vset(A, i, cmulc(c0, vget(A, i)));
  }

  // CNOT(0,1): lanes with q0=1 flip local bit5 (pure per-lane swap)
#pragma unroll
  for (int i = 0; i < 32; ++i) {
    const int j = i | 32;
    __half2 lo = vget(A, i), hi = vget(A, j);
    vset(A, i, po ? hi : lo);
    vset(A, j, po ? lo : hi);
  }
  // CNOT(1,2)..(5,6): local chain; g_cnot<6,C,C+1> = qubits (C+1, C+2)
  chain_cnot<6, 0>(A);

  // merged-U sweep: qubit 0 (cross-lane), then qubits 1..6 (local)
  {
    float ce, se, cp, sp, cf, sf;
    load_sc(xr, ETA[0], PT[0], PHI[0], ce, se, cp, sp, cf, sf);
    C2 U00, U01, U10, U11;
    mk_U(ce, se, cp, sp, cf, sf, U00, U01, U10, U11);
    // out_lane = UA*mine + UB*partner;  UA = po?U11:U00, UB = po?U10:U01
    C2 UA, UB;
    UA.rr = po ? U11.rr : U00.rr; UA.mp = po ? U11.mp : U00.mp;
    UB.rr = po ? U10.rr : U01.rr; UB.mp = po ? U10.mp : U01.mp;
#pragma unroll
    for (int i = 0; i < 64; ++i) {
      __half2 m = vget(A, i), q = lx1(m);
      vset(A, i, __hfma2(UA.rr, m, __hfma2(UA.mp, swap2(m),
                 __hfma2(UB.rr, q, __hmul2(UB.mp, swap2(q))))));
    }
  }
  usweep_rec<6, 0>(A, [&](int W, C2& U00, C2& U01, C2& U10, C2& U11) {
    const int k = W + 1;   // g_u2<6,W> mask 1<<(5-W) == qubit k local bit 6-k
    float ce, se, cp, sp, cf, sf;
    load_sc(xr, ETA[k], PT[k], PHI[k], ce, se, cp, sp, cf, sf);
    mk_U(ce, se, cp, sp, cf, sf, U00, U01, U10, U11);
  });

  // depth loop kept rolled: body stays in L1I
#pragma unroll 1
  for (int d = 0; d < 4; ++d) {
    // P1 (t->l): flip q0..q3 iff parity(q4,q5,q6).  Pairs {i, i^0x38} across
    // lanes: A[i]_po <- old A[i^0x38]_{1-po}
#pragma unroll
    for (int i = 0; i < 64; ++i)
      if (parc(i & 7) && !(i & 0x20)) {
        const int j = i ^ 0x38;
        __half2 t0 = lx1(vget(A, j));
        __half2 t1 = lx1(vget(A, i));
        vset(A, i, t0); vset(A, j, t1);
      }

    // Ry qubit 0 (cross-lane): out = c*mine + (po? s : -s)*partner
    {
      float sv, cv; __sincosf(0.5f * wD[7 * d], &sv, &cv);
      __half2 c2v = __floats2half2_rn(cv, cv);
      __half2 sp2 = __floats2half2_rn(po ? sv : -sv, po ? sv : -sv);
#pragma unroll
      for (int i = 0; i < 64; ++i) {
        __half2 q = lx1(vget(A, i));
        vset(A, i, __hfma2(c2v, vget(A, i), __hmul2(sp2, q)));
      }
    }
    // Ry qubits 1..6 (local)
    ry_rec<6, 0>(A, [&](int W, __half2& c2, __half2& s2, __half2& ns2) {
      float sv, cv; __sincosf(0.5f * wD[7 * d + W + 1], &sv, &cv);
      c2 = __floats2half2_rn(cv, cv);
      s2 = __floats2half2_rn(sv, sv);
      ns2 = __floats2half2_rn(-sv, -sv);
    });

    // P2 (l->t): flip q4..q6 (local ^7) iff parity(q0..q3) = po ^ parc(i&0x38)
#pragma unroll
    for (int i = 0; i < 64; ++i)
      if (!(i & 4)) {            // rep of pair {i, i^7}
        const int j = i ^ 7;
        const bool cond = parc(i & 0x38) ? !po : po;
        __half2 lo = vget(A, i), hi = vget(A, j);
        vset(A, i, cond ? hi : lo);
        vset(A, j, cond ? lo : hi);
      }
  }

  // readout: class c = q4q5q6 = i&7 (local); pair-sum cross-lane
  float cls[8];
#pragma unroll
  for (int c = 0; c < 8; ++c) cls[c] = 0.f;
#pragma unroll
  for (int i = 0; i < 64; ++i) cls[i & 7] = ampsq(vget(A, i), cls[i & 7]);
  float z4 = 0.f, z5 = 0.f, z6 = 0.f;
#pragma unroll
  for (int c = 0; c < 8; ++c) {
    z4 += (c & 4) ? -cls[c] : cls[c];
    z5 += (c & 2) ? -cls[c] : cls[c];
    z6 += (c & 1) ? -cls[c] : cls[c];
  }
  z4 += lx1f(z4); z5 += lx1f(z5); z6 += lx1f(z6);
  if (!po) {
    out_row[6] = z4; out_row[7] = z5; out_row[8] = z6;
  }
}

// ---------------- fused kernel: 256 threads = 4 waves per 64-element chunk --

__global__ void
__attribute__((amdgpu_flat_work_group_size(256, 256), amdgpu_waves_per_eu(2, 4)))
k_all(const float* __restrict__ x,
      const float* __restrict__ wA, const float* __restrict__ wB,
      const float* __restrict__ wC, const float* __restrict__ wD,
      float* __restrict__ out, int B) {
  const int base = blockIdx.x * 64;
  const int wv = threadIdx.x >> 6;       // wave id 0..3 (uniform per wave)
  const int lane = threadIdx.x & 63;

  if (wv == 0) {
    // sims A+B for 64 elements
    const int b = base + lane;
    if (b >= B) return;
    const float* xr = x + (size_t)b * 56;
    float o[4];
    sim4h<0>(xr, wA, &o[0]);
    sim4h<1>(xr, wB, &o[2]);
    float* op = out + (size_t)b * 9;
    op[0] = o[0]; op[1] = o[1]; op[2] = o[2]; op[3] = o[3];
  } else if (wv == 3) {
    // sim C for 64 elements
    const int b = base + lane;
    if (b >= B) return;
    const float* xr = x + (size_t)b * 56;
    float o[2];
    sim4h<2>(xr, wC, o);
    float* op = out + (size_t)b * 9;
    op[4] = o[0]; op[5] = o[1];
  } else {
    // waves 1,2: 7q. wave1 -> elements base+0..31, wave2 -> base+32..63
    const int p = (wv - 1) * 32 + (lane >> 1);
    const int b = base + p;
    if (b >= B) return;
    const bool po = (lane & 1) != 0;
    role7(x + (size_t)b * 56, wD, out + (size_t)b * 9, po);
  }
}

// ---------------- launch ----------------------------------------------------

extern "C" void kernel_launch(void* const* d_in, const int* in_sizes, int n_in,
                              void* d_out, int out_size, void* d_ws, size_t ws_size,
                              hipStream_t stream) {
  const float* x  = (const float*)d_in[0];
  const float* wA = (const float*)d_in[1];
  const float* wB = (const float*)d_in[2];
  const float* wC = (const float*)d_in[3];
  const float* wD = (const float*)d_in[4];
  float* out = (float*)d_out;
  const int B = in_sizes[0] / 56;

  const int blocks = (B + 63) / 64;
  k_all<<<blocks, 256, 0, stream>>>(x, wA, wB, wC, wD, out, B);
}

// Round 9
// 138.373 us; speedup vs baseline: 1.0538x; 1.0538x over previous
//
#include <hip/hip_runtime.h>
#include <hip/hip_fp16.h>

// Batched quantum-circuit sim. ONE launch, 1-D grid, 256-thread blocks
// (the only launch shape that has ever passed in this harness), two
// UNIFORM block roles (R8 showed mixed-length waves in one block strand
// the workgroup slot; R6's uniform blocks packed better):
//  - blocks [0, gx):        ABC: one thread per element, runs sims A+B+C,
//                           writes out[b*9+0..5] (24B contiguous, one writer)
//  - blocks [gx, gx+gy):    7q sim, 2 lanes/element (qubit0 = lane parity),
//                           writes out[b*9+6..8]
// __launch_bounds__(256,2): min 2 waves/EU, NO occupancy max (R6/R8's
// waves_per_eu(2,4) capped residency at 4/SIMD; VGPR=76 permits 6).
// State in ext_vector_type SSA vectors (R6 proved register residency).

#define DEVINL __device__ __forceinline__

typedef _Float16 hv2 __attribute__((ext_vector_type(2)));
typedef unsigned int u32;
typedef u32 vreg16 __attribute__((ext_vector_type(16)));
typedef u32 vreg64 __attribute__((ext_vector_type(64)));

struct C2 { __half2 rr, mp; };  // complex const (r,i): rr=(r,r), mp=(-i,+i)

DEVINL C2 mkc(float re, float im) {
  C2 c; c.rr = __floats2half2_rn(re, re); c.mp = __floats2half2_rn(-im, im); return c;
}
DEVINL __half2 mkamp(float re, float im) { return __floats2half2_rn(re, im); }
DEVINL __half2 swap2(__half2 v) { return __lowhigh2highlow(v); }
// (const u) * (amp v):  (r*vr - i*vi, r*vi + i*vr)
DEVINL __half2 cmulc(C2 u, __half2 v) { return __hfma2(u.rr, v, __hmul2(u.mp, swap2(v))); }

DEVINL float ampsq(__half2 v, float acc) {
#if __has_builtin(__builtin_amdgcn_fdot2)
  return __builtin_amdgcn_fdot2(__builtin_bit_cast(hv2, v), __builtin_bit_cast(hv2, v), acc, false);
#else
  float2 f = __half22float2(v);
  return fmaf(f.x, f.x, fmaf(f.y, f.y, acc));
#endif
}

constexpr int parc(int x) { x ^= x >> 4; x ^= x >> 2; x ^= x >> 1; return x & 1; }

struct c32 { float x, y; };
DEVINL c32 cmulf(c32 a, c32 b) { return { a.x*b.x - a.y*b.y, a.x*b.y + a.y*b.x }; }

// ---- SSA state accessors (constant-index extract/insert) -------------------
template<class VT>
DEVINL __half2 vget(const VT& A, int i) { return __builtin_bit_cast(__half2, (u32)A[i]); }
template<class VT>
DEVINL void vset(VT& A, int i, __half2 v) { A[i] = __builtin_bit_cast(u32, v); }

// ---- lane^1 exchange via shfl_xor (verified path from R3) ------------------
DEVINL __half2 lx1(__half2 v) {
  int q = __shfl_xor(__builtin_bit_cast(int, v), 1, 64);
  return __builtin_bit_cast(__half2, q);
}
DEVINL float lx1f(float v) { return __shfl_xor(v, 1, 64); }

// ---------------- generic gates (qubit W of N; mask = 1<<(N-1-W)) -----------

template<int N, int W, class VT>
DEVINL void g_ry(VT& A, __half2 c2, __half2 s2, __half2 ns2) {
  constexpr int M = 1 << (N - 1 - W);
#pragma unroll
  for (int i = 0; i < (1 << N); ++i) if (!(i & M)) {
    const int j = i | M;
    __half2 v0 = vget(A, i), v1 = vget(A, j);
    vset(A, i, __hfma2(c2, v0, __hmul2(ns2, v1)));
    vset(A, j, __hfma2(c2, v1, __hmul2(s2, v0)));
  }
}

template<int N, int W, class VT>
DEVINL void g_u2(VT& A, C2 u00, C2 u01, C2 u10, C2 u11) {
  constexpr int M = 1 << (N - 1 - W);
#pragma unroll
  for (int i = 0; i < (1 << N); ++i) if (!(i & M)) {
    const int j = i | M;
    __half2 v0 = vget(A, i), v1 = vget(A, j), v0s = swap2(v0), v1s = swap2(v1);
    vset(A, i, __hfma2(u00.rr, v0, __hfma2(u00.mp, v0s, __hfma2(u01.rr, v1, __hmul2(u01.mp, v1s)))));
    vset(A, j, __hfma2(u10.rr, v0, __hfma2(u10.mp, v0s, __hfma2(u11.rr, v1, __hmul2(u11.mp, v1s)))));
  }
}

template<int N, int C, int T, class VT>
DEVINL void g_cnot(VT& A) {
  constexpr int CM = 1 << (N - 1 - C), TM = 1 << (N - 1 - T);
#pragma unroll
  for (int i = 0; i < (1 << N); ++i) if ((i & CM) && !(i & TM)) {
    const int j = i | TM;
    __half2 t = vget(A, i); vset(A, i, vget(A, j)); vset(A, j, t);
  }
}

template<int N, int K, class VT>
DEVINL void chain_cnot(VT& A) {
  if constexpr (K < N - 1) { g_cnot<N, K, K + 1>(A); chain_cnot<N, K + 1>(A); }
}

// ---------------- per-qubit coefficients (f32) ------------------------------
// forward: u = Rz(phi)Ry(pt)Rx(eta)|0>;  reverse merged: U = Rx(phi)Ry(pt)Rz(eta)

DEVINL void mk_u01(float ce, float se, float cp, float sp, float cf, float sf,
                   c32& u0, c32& u1) {
  u0 = cmulf({cf, -sf}, {cp * ce, sp * se});
  u1 = cmulf({cf,  sf}, {sp * ce, -cp * se});
}

DEVINL void mk_U(float ce, float se, float cp, float sp, float cf, float sf,
                 C2& U00, C2& U01, C2& U10, C2& U11) {
  c32 z = {ce, -se}, zb = {ce, se};
  c32 A = cmulf({cf * cp, -sf * sp}, z);
  c32 T = cmulf({cf * sp,  sf * cp}, zb);
  c32 Cc = cmulf({cf * sp, -sf * cp}, z);
  c32 D = cmulf({cf * cp,  sf * sp}, zb);
  U00 = mkc(A.x, A.y); U01 = mkc(-T.x, -T.y); U10 = mkc(Cc.x, Cc.y); U11 = mkc(D.x, D.y);
}

// per-qubit sincos loader (eta_i<0 -> eta=0)
DEVINL void load_sc(const float* __restrict__ xr, int eta_i, int pt_i, int phi_i,
                    float& ce, float& se, float& cp, float& sp, float& cf, float& sf) {
  float e = (eta_i < 0) ? 0.f : xr[eta_i];
  __sincosf(0.5f * e, &se, &ce);
  __sincosf(0.5f * xr[pt_i], &sp, &cp);
  __sincosf(0.5f * xr[phi_i], &sf, &cf);
}

// product state build by doubling (A[0] must be (1,0) on entry).
// step M's qubit lands at bit (N-1-M). CF(M,u0,u1) supplies the column.
template<int N, int M, class VT, class CF>
DEVINL void build_rec(VT& A, CF cf) {
  if constexpr (M < N) {
    c32 u0, u1; cf(M, u0, u1);
    C2 c0 = mkc(u0.x, u0.y), c1 = mkc(u1.x, u1.y);
#pragma unroll
    for (int j = (1 << M) - 1; j >= 0; --j) {
      __half2 s = vget(A, j);
      vset(A, 2 * j,     cmulc(c0, s));
      vset(A, 2 * j + 1, cmulc(c1, s));
    }
    build_rec<N, M + 1>(A, cf);
  }
}

template<int N, int K, class VT, class CF>
DEVINL void usweep_rec(VT& A, CF cf) {
  if constexpr (K < N) {
    C2 U00, U01, U10, U11;
    cf(K, U00, U01, U10, U11);
    g_u2<N, K>(A, U00, U01, U10, U11);
    usweep_rec<N, K + 1>(A, cf);
  }
}

template<int N, int K, class VT, class CF>
DEVINL void ry_rec(VT& A, CF cf) {
  if constexpr (K < N) {
    __half2 c2, s2, ns2;
    cf(K, c2, s2, ns2);
    g_ry<N, K>(A, c2, s2, ns2);
    ry_rec<N, K + 1>(A, cf);
  }
}

// ---------------- 4-qubit block I (verified math, SSA state) ----------------

template<int I>
DEVINL void sim4h(const float* __restrict__ xr, const float* __restrict__ w, float* z) {
  constexpr int PT[3][4]  = {{5, 4, 35, 34}, {3, 33, 31, 2}, {28, 32, 15, 16}};
  constexpr int ETA[3][4] = {{9, 8, 45, 44}, {7, 43, 41, 6}, {38, 42, 19, 20}};
  constexpr int PHI[3][4] = {{13, 12, 55, 54}, {11, 53, 51, 10}, {48, 52, 23, 24}};
  vreg16 A;
  vset(A, 0, mkamp(1.f, 0.f));
  build_rec<4, 0>(A, [&](int M, c32& u0, c32& u1) {
    float ce, se, cp, sp, cf, sf;
    load_sc(xr, ETA[I][M], PT[I][M], PHI[I][M], ce, se, cp, sp, cf, sf);
    mk_u01(ce, se, cp, sp, cf, sf, u0, u1);
  });
  chain_cnot<4, 0>(A);
  usweep_rec<4, 0>(A, [&](int K, C2& U00, C2& U01, C2& U10, C2& U11) {
    float ce, se, cp, sp, cf, sf;
    load_sc(xr, ETA[I][K], PT[I][K], PHI[I][K], ce, se, cp, sp, cf, sf);
    mk_U(ce, se, cp, sp, cf, sf, U00, U01, U10, U11);
  });

  // t->l CNOT block == flip q0,q1 (mask 12) iff parity(b2,b3) (i&3)
#pragma unroll
  for (int i = 0; i < 16; ++i)
    if (parc(i & 3) && !(i & 8)) {
      __half2 t = vget(A, i); vset(A, i, vget(A, i ^ 12)); vset(A, i ^ 12, t);
    }

  ry_rec<4, 0>(A, [&](int K, __half2& c2, __half2& s2, __half2& ns2) {
    float sv, cv; __sincosf(0.5f * w[K], &sv, &cv);
    c2 = __floats2half2_rn(cv, cv);
    s2 = __floats2half2_rn(sv, sv);
    ns2 = __floats2half2_rn(-sv, -sv);
  });

  // l->t CNOT block == flip q2,q3 (mask 3) iff parity(b0,b1) (i&12)
#pragma unroll
  for (int i = 0; i < 16; ++i)
    if (parc(i & 12) && !(i & 2)) {
      __half2 t = vget(A, i); vset(A, i, vget(A, i ^ 3)); vset(A, i ^ 3, t);
    }

  float cls[4];
#pragma unroll
  for (int c = 0; c < 4; ++c) cls[c] = 0.f;
#pragma unroll
  for (int i = 0; i < 16; ++i) cls[i & 3] = ampsq(vget(A, i), cls[i & 3]);
  float z0 = 0.f, z1 = 0.f;
#pragma unroll
  for (int c = 0; c < 4; ++c) {
    z0 += (c & 2) ? -cls[c] : cls[c];
    z1 += (c & 1) ? -cls[c] : cls[c];
  }
  z[0] = z0; z[1] = z1;
}

// ---------------- 7q body (2 lanes/element; verified R3/R6 math) ------------

DEVINL void role7(const float* __restrict__ xr, const float* __restrict__ wD,
                  float* __restrict__ out_row, bool po) {
  constexpr int PT[7]  = {0, 14, 30, 26, 29, 27, 17};
  constexpr int ETA[7] = {-1, 18, 40, 36, 39, 37, 21};  // -1 -> zeros (None)
  constexpr int PHI[7] = {1, 22, 50, 46, 49, 47, 25};

  vreg64 A;
  vset(A, 0, mkamp(1.f, 0.f));
  // build qubits 1..6 locally: step M = qubit M+1 -> local bit 5-M = 6-(M+1)
  build_rec<6, 0>(A, [&](int M, c32& u0, c32& u1) {
    const int k = M + 1;
    float ce, se, cp, sp, cf, sf;
    load_sc(xr, ETA[k], PT[k], PHI[k], ce, se, cp, sp, cf, sf);
    mk_u01(ce, se, cp, sp, cf, sf, u0, u1);
  });
  { // qubit-0 product factor, selected by lane parity
    float ce, se, cp, sp, cf, sf;
    load_sc(xr, ETA[0], PT[0], PHI[0], ce, se, cp, sp, cf, sf);
    c32 u0, u1; mk_u01(ce, se, cp, sp, cf, sf, u0, u1);
    C2 c0 = mkc(po ? u1.x : u0.x, po ? u1.y : u0.y);
#pragma unroll
    for (int i = 0; i < 64; ++i) vset(A, i, cmulc(c0, vget(A, i)));
  }

  // CNOT(0,1): lanes with q0=1 flip local bit5 (pure per-lane swap)
#pragma unroll
  for (int i = 0; i < 32; ++i) {
    const int j = i | 32;
    __half2 lo = vget(A, i), hi = vget(A, j);
    vset(A, i, po ? hi : lo);
    vset(A, j, po ? lo : hi);
  }
  // CNOT(1,2)..(5,6): local chain; g_cnot<6,C,C+1> = qubits (C+1, C+2)
  chain_cnot<6, 0>(A);

  // merged-U sweep: qubit 0 (cross-lane), then qubits 1..6 (local)
  {
    float ce, se, cp, sp, cf, sf;
    load_sc(xr, ETA[0], PT[0], PHI[0], ce, se, cp, sp, cf, sf);
    C2 U00, U01, U10, U11;
    mk_U(ce, se, cp, sp, cf, sf, U00, U01, U10, U11);
    // out_lane = UA*mine + UB*partner;  UA = po?U11:U00, UB = po?U10:U01
    C2 UA, UB;
    UA.rr = po ? U11.rr : U00.rr; UA.mp = po ? U11.mp : U00.mp;
    UB.rr = po ? U10.rr : U01.rr; UB.mp = po ? U10.mp : U01.mp;
#pragma unroll
    for (int i = 0; i < 64; ++i) {
      __half2 m = vget(A, i), q = lx1(m);
      vset(A, i, __hfma2(UA.rr, m, __hfma2(UA.mp, swap2(m),
                 __hfma2(UB.rr, q, __hmul2(UB.mp, swap2(q))))));
    }
  }
  usweep_rec<6, 0>(A, [&](int W, C2& U00, C2& U01, C2& U10, C2& U11) {
    const int k = W + 1;   // g_u2<6,W> mask 1<<(5-W) == qubit k local bit 6-k
    float ce, se, cp, sp, cf, sf;
    load_sc(xr, ETA[k], PT[k], PHI[k], ce, se, cp, sp, cf, sf);
    mk_U(ce, se, cp, sp, cf, sf, U00, U01, U10, U11);
  });

  // depth loop kept rolled: body stays in L1I
#pragma unroll 1
  for (int d = 0; d < 4; ++d) {
    // P1 (t->l): flip q0..q3 iff parity(q4,q5,q6).  Pairs {i, i^0x38} across
    // lanes: A[i]_po <- old A[i^0x38]_{1-po}
#pragma unroll
    for (int i = 0; i < 64; ++i)
      if (parc(i & 7) && !(i & 0x20)) {
        const int j = i ^ 0x38;
        __half2 t0 = lx1(vget(A, j));
        __half2 t1 = lx1(vget(A, i));
        vset(A, i, t0); vset(A, j, t1);
      }

    // Ry qubit 0 (cross-lane): out = c*mine + (po? s : -s)*partner
    {
      float sv, cv; __sincosf(0.5f * wD[7 * d], &sv, &cv);
      __half2 c2v = __floats2half2_rn(cv, cv);
      __half2 sp2 = __floats2half2_rn(po ? sv : -sv, po ? sv : -sv);
#pragma unroll
      for (int i = 0; i < 64; ++i) {
        __half2 q = lx1(vget(A, i));
        vset(A, i, __hfma2(c2v, vget(A, i), __hmul2(sp2, q)));
      }
    }
    // Ry qubits 1..6 (local)
    ry_rec<6, 0>(A, [&](int W, __half2& c2, __half2& s2, __half2& ns2) {
      float sv, cv; __sincosf(0.5f * wD[7 * d + W + 1], &sv, &cv);
      c2 = __floats2half2_rn(cv, cv);
      s2 = __floats2half2_rn(sv, sv);
      ns2 = __floats2half2_rn(-sv, -sv);
    });

    // P2 (l->t): flip q4..q6 (local ^7) iff parity(q0..q3) = po ^ parc(i&0x38)
#pragma unroll
    for (int i = 0; i < 64; ++i)
      if (!(i & 4)) {            // rep of pair {i, i^7}
        const int j = i ^ 7;
        const bool cond = parc(i & 0x38) ? !po : po;
        __half2 lo = vget(A, i), hi = vget(A, j);
        vset(A, i, cond ? hi : lo);
        vset(A, j, cond ? lo : hi);
      }
  }

  // readout: class c = q4q5q6 = i&7 (local); pair-sum cross-lane
  float cls[8];
#pragma unroll
  for (int c = 0; c < 8; ++c) cls[c] = 0.f;
#pragma unroll
  for (int i = 0; i < 64; ++i) cls[i & 7] = ampsq(vget(A, i), cls[i & 7]);
  float z4 = 0.f, z5 = 0.f, z6 = 0.f;
#pragma unroll
  for (int c = 0; c < 8; ++c) {
    z4 += (c & 4) ? -cls[c] : cls[c];
    z5 += (c & 2) ? -cls[c] : cls[c];
    z6 += (c & 1) ? -cls[c] : cls[c];
  }
  z4 += lx1f(z4); z5 += lx1f(z5); z6 += lx1f(z6);
  if (!po) {
    out_row[6] = z4; out_row[7] = z5; out_row[8] = z6;
  }
}

// ---------------- single fused-dispatch kernel ------------------------------

__global__ void __launch_bounds__(256, 2)
k_all(const float* __restrict__ x,
      const float* __restrict__ wA, const float* __restrict__ wB,
      const float* __restrict__ wC, const float* __restrict__ wD,
      float* __restrict__ out, int B, int gx) {
  const int bx = blockIdx.x;
  if (bx < gx) {
    // ABC role: one thread per element, all three 4q sims
    const int b = bx * 256 + threadIdx.x;
    if (b >= B) return;
    const float* xr = x + (size_t)b * 56;
    float o[6];
    sim4h<0>(xr, wA, &o[0]);
    sim4h<1>(xr, wB, &o[2]);
    sim4h<2>(xr, wC, &o[4]);
    float* op = out + (size_t)b * 9;
#pragma unroll
    for (int i = 0; i < 6; ++i) op[i] = o[i];
  } else {
    // 7q role: 2 lanes per element
    const int t = (bx - gx) * 256 + threadIdx.x;
    const int b = t >> 1;
    if (b >= B) return;
    const bool po = (t & 1) != 0;
    role7(x + (size_t)b * 56, wD, out + (size_t)b * 9, po);
  }
}

// ---------------- launch ----------------------------------------------------

extern "C" void kernel_launch(void* const* d_in, const int* in_sizes, int n_in,
                              void* d_out, int out_size, void* d_ws, size_t ws_size,
                              hipStream_t stream) {
  const float* x  = (const float*)d_in[0];
  const float* wA = (const float*)d_in[1];
  const float* wB = (const float*)d_in[2];
  const float* wC = (const float*)d_in[3];
  const float* wD = (const float*)d_in[4];
  float* out = (float*)d_out;
  const int B = in_sizes[0] / 56;
  const int threads = 256;

  const int gx = (B + threads - 1) / threads;          // ABC blocks
  const int gy = (2 * B + threads - 1) / threads;      // 7q blocks
  k_all<<<gx + gy, threads, 0, stream>>>(x, wA, wB, wC, wD, out, B, gx);
}